// Round 2
// baseline (192.509 us; speedup 1.0000x reference)
//
#include <hip/hip_runtime.h>

// Problem: B=32, S=256, M=1024, N=32, O=32.
// out[b][s*32+o] = sum_k exp(-sum_n |proj[b,s,n,o]-proj[b,k,n,o]|),
// proj[b,s,j] = sum_m x[b,s,m] W[j,m],  j = n*32+o.

#define BS 8192      // B*S rows of x
#define MD 1024      // M
#define NO 1024      // N*O
#define KSPLIT 4
#define KTILE 64     // 256 / KSPLIT

typedef short short8 __attribute__((ext_vector_type(8)));    // 8 bf16 raw bits
typedef float f32x4 __attribute__((ext_vector_type(4)));
typedef _Float16 f16x2 __attribute__((ext_vector_type(2)));

template <typename T, typename F>
__device__ __forceinline__ T bc(F f) { return __builtin_bit_cast(T, f); }

// ---------------- cast f32 -> bf16 (RNE), 4 elems/thread ----------------
__global__ __launch_bounds__(256) void cast_bf16_kernel(const float* __restrict__ in,
                                                        unsigned short* __restrict__ out,
                                                        int n4) {
  int i = blockIdx.x * 256 + threadIdx.x;
  if (i >= n4) return;
  float4 v = reinterpret_cast<const float4*>(in)[i];
  ushort4 u;
  unsigned b;
  b = __float_as_uint(v.x); u.x = (unsigned short)((b + 0x7FFFu + ((b >> 16) & 1u)) >> 16);
  b = __float_as_uint(v.y); u.y = (unsigned short)((b + 0x7FFFu + ((b >> 16) & 1u)) >> 16);
  b = __float_as_uint(v.z); u.z = (unsigned short)((b + 0x7FFFu + ((b >> 16) & 1u)) >> 16);
  b = __float_as_uint(v.w); u.w = (unsigned short)((b + 0x7FFFu + ((b >> 16) & 1u)) >> 16);
  reinterpret_cast<ushort4*>(out)[i] = u;
}

// ---------------- GEMM: projT[j][i] = sum_k W[j,k] x[i,k], emitted as
// projP[m][o][i] = packed f16x2 (proj[n=2m], proj[n=2m+1]) for column o ----
// Wave computes a 64(j) x 64(i) tile with mfma_f32_16x16x32_bf16.
// A-frag: row=lane&15, k=(lane>>4)*8+e ; B-frag: col=lane&15, same k.
// D-frag: col=lane&15, row=(lane>>4)*4+reg.   (per guide, m89-verified)
__global__ __launch_bounds__(256) void gemm_kernel(const unsigned short* __restrict__ xb,
                                                   const unsigned short* __restrict__ wb,
                                                   unsigned int* __restrict__ projP) {
  const int lane = threadIdx.x & 63;
  const int w = threadIdx.x >> 6;
  const int wj = w >> 1, wi = w & 1;
  const int jt = blockIdx.y * 128 + wj * 64;   // multiple of 64
  const int it = blockIdx.x * 128 + wi * 64;
  const int c = lane & 15, h = lane >> 4;

  f32x4 acc[4][4];
#pragma unroll
  for (int m = 0; m < 4; m++)
#pragma unroll
    for (int n = 0; n < 4; n++) acc[m][n] = f32x4{0.f, 0.f, 0.f, 0.f};

  const unsigned short* wptr = wb + (size_t)(jt + c) * MD + h * 8;
  const unsigned short* xptr = xb + (size_t)(it + c) * MD + h * 8;

  for (int k0 = 0; k0 < MD; k0 += 32) {
    short8 a[4], bfr[4];
#pragma unroll
    for (int mm = 0; mm < 4; mm++)
      a[mm] = *reinterpret_cast<const short8*>(wptr + mm * 16 * MD + k0);
#pragma unroll
    for (int nn = 0; nn < 4; nn++)
      bfr[nn] = *reinterpret_cast<const short8*>(xptr + nn * 16 * MD + k0);
#pragma unroll
    for (int mm = 0; mm < 4; mm++)
#pragma unroll
      for (int nn = 0; nn < 4; nn++)
        acc[mm][nn] = __builtin_amdgcn_mfma_f32_16x16x32_bf16(a[mm], bfr[nn], acc[mm][nn], 0, 0, 0);
  }

  // epilogue: j = jt + 16*mm + 4*h + r -> n = j>>5 (pair), o = j&31
  const int mglob = jt >> 6;  // n-pair index
#pragma unroll
  for (int mm01 = 0; mm01 < 2; mm01++) {
#pragma unroll
    for (int r = 0; r < 4; r++) {
      const int o = mm01 * 16 + h * 4 + r;
      unsigned int* orow = projP + (size_t)(mglob * 32 + o) * BS + it + c;
#pragma unroll
      for (int nn = 0; nn < 4; nn++) {
        orow[nn * 16] = bc<unsigned int>(
            __builtin_amdgcn_cvt_pkrtz(acc[mm01][nn][r], acc[mm01 + 2][nn][r]));
      }
    }
  }
}

// ---------------- phase 2: distances + exp, packed f16 ----------------
// block: 64 threads = 1 wave; blockIdx -> (b, o, ks). Thread t owns rows
// i = t + 64*r (r=0..3). d(i,k) = 2*Smax - A_i - A_k ; out += exp2(-d*log2e)
__global__ __launch_bounds__(64) void dist_kernel(const unsigned int* __restrict__ projP,
                                                  float* __restrict__ part) {
  const int t = threadIdx.x;
  const int bid = blockIdx.x;
  const int ks = bid & (KSPLIT - 1);
  const int bo = bid >> 2;
  const int o = bo & 31, b = bo >> 5;
  const int ibase = b * 256;

  __shared__ unsigned int kv_lds[16][KTILE];  // 4 KB
  __shared__ float A_lds[KTILE];

  // stage k-tile (coalesced, conflict-free)
#pragma unroll
  for (int m = 0; m < 16; m++)
    kv_lds[m][t] = projP[(size_t)(m * 32 + o) * BS + ibase + ks * KTILE + t];

  // per-thread rows + A sums (A chain must bit-match the k-loop pk_add chain)
  f16x2 p2[4][16];
  float Af[4];
#pragma unroll
  for (int r = 0; r < 4; r++) {
    f16x2 a2 = bc<f16x2>(0u);
#pragma unroll
    for (int m = 0; m < 16; m++) {
      unsigned int g = projP[(size_t)(m * 32 + o) * BS + ibase + t + 64 * r];
      p2[r][m] = bc<f16x2>(g);
      a2 += p2[r][m];
    }
    Af[r] = (float)a2[0] + (float)a2[1];
  }
  A_lds[t] = Af[ks];  // row (ks*64 + t) is this thread's r=ks row
  __syncthreads();

  float outv[4] = {0.f, 0.f, 0.f, 0.f};
  for (int kk0 = 0; kk0 < KTILE; kk0 += 4) {
    f16x2 s2[4][4];
#pragma unroll
    for (int r = 0; r < 4; r++)
#pragma unroll
      for (int q = 0; q < 4; q++) s2[r][q] = bc<f16x2>(0u);

#pragma unroll
    for (int m = 0; m < 16; m++) {
      uint4 kw = *reinterpret_cast<const uint4*>(&kv_lds[m][kk0]);  // broadcast b128
      f16x2 k0 = bc<f16x2>(kw.x), k1 = bc<f16x2>(kw.y);
      f16x2 k2 = bc<f16x2>(kw.z), k3 = bc<f16x2>(kw.w);
#pragma unroll
      for (int r = 0; r < 4; r++) {
        s2[r][0] += __builtin_elementwise_max(p2[r][m], k0);
        s2[r][1] += __builtin_elementwise_max(p2[r][m], k1);
        s2[r][2] += __builtin_elementwise_max(p2[r][m], k2);
        s2[r][3] += __builtin_elementwise_max(p2[r][m], k3);
      }
    }
    float4 ak = *reinterpret_cast<const float4*>(&A_lds[kk0]);
    float akv[4] = {ak.x, ak.y, ak.z, ak.w};
#pragma unroll
    for (int r = 0; r < 4; r++)
#pragma unroll
      for (int q = 0; q < 4; q++) {
        float S = (float)s2[r][q][0] + (float)s2[r][q][1];
        outv[r] += exp2f((Af[r] + akv[q] - 2.0f * S) * 1.4426950408889634f);
      }
  }

#pragma unroll
  for (int r = 0; r < 4; r++)
    part[(size_t)((ks * 32 + b) * 32 + o) * 256 + t + 64 * r] = outv[r];
}

// ---------------- reduce KSPLIT partials + transpose [o][s] -> [s*32+o] ----
__global__ __launch_bounds__(256) void reduce_kernel(const float* __restrict__ part,
                                                     float* __restrict__ out) {
  const int b = blockIdx.x;
  __shared__ float T[32][257];
  for (int l = threadIdx.x; l < 8192; l += 256) {
    int o = l >> 8, s = l & 255;
    float v = 0.f;
#pragma unroll
    for (int ks = 0; ks < KSPLIT; ks++)
      v += part[(size_t)((ks * 32 + b) * 32 + o) * 256 + s];
    T[o][s] = v;
  }
  __syncthreads();
  for (int l = threadIdx.x; l < 8192; l += 256)
    out[(size_t)b * 8192 + l] = T[l & 31][l >> 5];
}

extern "C" void kernel_launch(void* const* d_in, const int* in_sizes, int n_in,
                              void* d_out, int out_size, void* d_ws, size_t ws_size,
                              hipStream_t stream) {
  const float* x = (const float*)d_in[0];   // (32,256,1024) f32
  const float* W = (const float*)d_in[1];   // (1024,1024) f32
  float* out = (float*)d_out;               // (32, 8192) f32

  char* ws = (char*)d_ws;
  unsigned short* xb = (unsigned short*)ws;                          // 16 MB
  unsigned short* wbf = (unsigned short*)(ws + (16u << 20));         //  2 MB
  unsigned int* projP = (unsigned int*)(ws + (18u << 20));           // 16 MB
  float* part = (float*)(ws + (34u << 20));                          //  4 MB

  {
    int n4 = (BS * MD) / 4;  // 2097152
    cast_bf16_kernel<<<(n4 + 255) / 256, 256, 0, stream>>>(x, xb, n4);
  }
  {
    int n4 = (NO * MD) / 4;  // 262144
    cast_bf16_kernel<<<(n4 + 255) / 256, 256, 0, stream>>>(W, wbf, n4);
  }
  {
    dim3 grid(BS / 128, NO / 128);  // (64, 8)
    gemm_kernel<<<grid, 256, 0, stream>>>(xb, wbf, projP);
  }
  dist_kernel<<<32 * 32 * KSPLIT, 64, 0, stream>>>(projP, part);
  reduce_kernel<<<32, 256, 0, stream>>>(part, out);
}

// Round 3
// 178.308 us; speedup vs baseline: 1.0796x; 1.0796x over previous
//
#include <hip/hip_runtime.h>

// Problem: B=32, S=256, M=1024, N=32, O=32.
// out[b][s*32+o] = sum_k exp(-sum_n |proj[b,s,n,o]-proj[b,k,n,o]|),
// proj[b,s,j] = sum_m x[b,s,m] W[j,m],  j = n*32+o.

#define BS 8192      // B*S rows of x
#define MD 1024      // M
#define NO 1024      // N*O
#define KSPLIT 4
#define KTILE 64     // 256 / KSPLIT

typedef short short8 __attribute__((ext_vector_type(8)));    // 8 bf16 raw bits
typedef float f32x4 __attribute__((ext_vector_type(4)));
typedef _Float16 f16x2 __attribute__((ext_vector_type(2)));

template <typename T, typename F>
__device__ __forceinline__ T bc(F f) { return __builtin_bit_cast(T, f); }

// packed f16 ops pinned to the VOP3P instructions (compiler was scalarizing)
__device__ __forceinline__ unsigned pk_max(unsigned a, unsigned b) {
  unsigned d;
  asm("v_pk_max_f16 %0, %1, %2" : "=v"(d) : "v"(a), "v"(b));
  return d;
}
__device__ __forceinline__ unsigned pk_add(unsigned a, unsigned b) {
  unsigned d;
  asm("v_pk_add_f16 %0, %1, %2" : "=v"(d) : "v"(a), "v"(b));
  return d;
}

// ---------------- cast f32 -> bf16 (RNE), 4 elems/thread ----------------
__global__ __launch_bounds__(256) void cast_bf16_kernel(const float* __restrict__ in,
                                                        unsigned short* __restrict__ out,
                                                        int n4) {
  int i = blockIdx.x * 256 + threadIdx.x;
  if (i >= n4) return;
  float4 v = reinterpret_cast<const float4*>(in)[i];
  ushort4 u;
  unsigned b;
  b = __float_as_uint(v.x); u.x = (unsigned short)((b + 0x7FFFu + ((b >> 16) & 1u)) >> 16);
  b = __float_as_uint(v.y); u.y = (unsigned short)((b + 0x7FFFu + ((b >> 16) & 1u)) >> 16);
  b = __float_as_uint(v.z); u.z = (unsigned short)((b + 0x7FFFu + ((b >> 16) & 1u)) >> 16);
  b = __float_as_uint(v.w); u.w = (unsigned short)((b + 0x7FFFu + ((b >> 16) & 1u)) >> 16);
  reinterpret_cast<ushort4*>(out)[i] = u;
}

// ---------------- GEMM: projT[j][i] = sum_k W[j,k] x[i,k], emitted as
// projP[m][o][i] = packed f16x2 (proj[n=2m], proj[n=2m+1]) for column o ----
__global__ __launch_bounds__(256) void gemm_kernel(const unsigned short* __restrict__ xb,
                                                   const unsigned short* __restrict__ wb,
                                                   unsigned int* __restrict__ projP) {
  const int lane = threadIdx.x & 63;
  const int w = threadIdx.x >> 6;
  const int wj = w >> 1, wi = w & 1;
  const int jt = blockIdx.y * 128 + wj * 64;   // multiple of 64
  const int it = blockIdx.x * 128 + wi * 64;
  const int c = lane & 15, h = lane >> 4;

  f32x4 acc[4][4];
#pragma unroll
  for (int m = 0; m < 4; m++)
#pragma unroll
    for (int n = 0; n < 4; n++) acc[m][n] = f32x4{0.f, 0.f, 0.f, 0.f};

  const unsigned short* wptr = wb + (size_t)(jt + c) * MD + h * 8;
  const unsigned short* xptr = xb + (size_t)(it + c) * MD + h * 8;

  for (int k0 = 0; k0 < MD; k0 += 32) {
    short8 a[4], bfr[4];
#pragma unroll
    for (int mm = 0; mm < 4; mm++)
      a[mm] = *reinterpret_cast<const short8*>(wptr + mm * 16 * MD + k0);
#pragma unroll
    for (int nn = 0; nn < 4; nn++)
      bfr[nn] = *reinterpret_cast<const short8*>(xptr + nn * 16 * MD + k0);
#pragma unroll
    for (int mm = 0; mm < 4; mm++)
#pragma unroll
      for (int nn = 0; nn < 4; nn++)
        acc[mm][nn] = __builtin_amdgcn_mfma_f32_16x16x32_bf16(a[mm], bfr[nn], acc[mm][nn], 0, 0, 0);
  }

  // epilogue: j = jt + 16*mm + 4*h + r -> n = j>>5 (pair), o = j&31
  const int mglob = jt >> 6;  // n-pair index
#pragma unroll
  for (int mm01 = 0; mm01 < 2; mm01++) {
#pragma unroll
    for (int r = 0; r < 4; r++) {
      const int o = mm01 * 16 + h * 4 + r;
      unsigned int* orow = projP + (size_t)(mglob * 32 + o) * BS + it + c;
#pragma unroll
      for (int nn = 0; nn < 4; nn++) {
        orow[nn * 16] = bc<unsigned int>(
            __builtin_amdgcn_cvt_pkrtz(acc[mm01][nn][r], acc[mm01 + 2][nn][r]));
      }
    }
  }
}

// ---------------- phase 2: distances + exp, packed f16 via asm ----------------
// block: 64 threads = 1 wave; blockIdx -> (b, o, ks). Thread t owns rows
// i = t + 64*r (r=0..3). Sum|a-b| = 2*Smax - A_i - A_k ; out += exp2(-d*log2e)
__global__ __launch_bounds__(64) void dist_kernel(const unsigned int* __restrict__ projP,
                                                  float* __restrict__ part) {
  const int t = threadIdx.x;
  const int bid = blockIdx.x;
  const int ks = bid & (KSPLIT - 1);
  const int bo = bid >> 2;
  const int o = bo & 31, b = bo >> 5;
  const int ibase = b * 256;

  __shared__ unsigned int kv_lds[16][KTILE];  // 4 KB
  __shared__ float A_lds[KTILE];

  // stage k-tile (coalesced, conflict-free)
#pragma unroll
  for (int m = 0; m < 16; m++)
    kv_lds[m][t] = projP[(size_t)(m * 32 + o) * BS + ibase + ks * KTILE + t];

  // per-thread rows + A sums (A chain must bit-match the k-loop pk_add chain)
  unsigned p2[4][16];
  float Af[4];
#pragma unroll
  for (int r = 0; r < 4; r++) {
    unsigned a2 = 0u;
#pragma unroll
    for (int m = 0; m < 16; m++) {
      p2[r][m] = projP[(size_t)(m * 32 + o) * BS + ibase + t + 64 * r];
      a2 = pk_add(a2, p2[r][m]);
    }
    f16x2 af = bc<f16x2>(a2);
    Af[r] = (float)af[0] + (float)af[1];
  }
  A_lds[t] = Af[ks];  // row (ks*64 + t) is this thread's r=ks row
  __syncthreads();

  float outv[4] = {0.f, 0.f, 0.f, 0.f};
  for (int kk0 = 0; kk0 < KTILE; kk0 += 4) {
    unsigned s2[4][4];
#pragma unroll
    for (int r = 0; r < 4; r++)
#pragma unroll
      for (int q = 0; q < 4; q++) s2[r][q] = 0u;

#pragma unroll
    for (int m = 0; m < 16; m++) {
      uint4 kw = *reinterpret_cast<const uint4*>(&kv_lds[m][kk0]);  // broadcast b128
#pragma unroll
      for (int r = 0; r < 4; r++) {
        s2[r][0] = pk_add(s2[r][0], pk_max(p2[r][m], kw.x));
        s2[r][1] = pk_add(s2[r][1], pk_max(p2[r][m], kw.y));
        s2[r][2] = pk_add(s2[r][2], pk_max(p2[r][m], kw.z));
        s2[r][3] = pk_add(s2[r][3], pk_max(p2[r][m], kw.w));
      }
    }
    float4 ak = *reinterpret_cast<const float4*>(&A_lds[kk0]);
    float akv[4] = {ak.x, ak.y, ak.z, ak.w};
#pragma unroll
    for (int r = 0; r < 4; r++)
#pragma unroll
      for (int q = 0; q < 4; q++) {
        f16x2 sv = bc<f16x2>(s2[r][q]);
        float S = (float)sv[0] + (float)sv[1];
        outv[r] += exp2f((Af[r] + akv[q] - 2.0f * S) * 1.4426950408889634f);
      }
  }

#pragma unroll
  for (int r = 0; r < 4; r++)
    part[(size_t)((ks * 32 + b) * 32 + o) * 256 + t + 64 * r] = outv[r];
}

// ---------------- reduce KSPLIT partials + transpose [o][s] -> [s*32+o] ----
__global__ __launch_bounds__(256) void reduce_kernel(const float* __restrict__ part,
                                                     float* __restrict__ out) {
  const int b = blockIdx.x;
  __shared__ float T[32][257];
  for (int l = threadIdx.x; l < 8192; l += 256) {
    int o = l >> 8, s = l & 255;
    float v = 0.f;
#pragma unroll
    for (int ks = 0; ks < KSPLIT; ks++)
      v += part[(size_t)((ks * 32 + b) * 32 + o) * 256 + s];
    T[o][s] = v;
  }
  __syncthreads();
  for (int l = threadIdx.x; l < 8192; l += 256)
    out[(size_t)b * 8192 + l] = T[l & 31][l >> 5];
}

extern "C" void kernel_launch(void* const* d_in, const int* in_sizes, int n_in,
                              void* d_out, int out_size, void* d_ws, size_t ws_size,
                              hipStream_t stream) {
  const float* x = (const float*)d_in[0];   // (32,256,1024) f32
  const float* W = (const float*)d_in[1];   // (1024,1024) f32
  float* out = (float*)d_out;               // (32, 8192) f32

  char* ws = (char*)d_ws;
  unsigned short* xb = (unsigned short*)ws;                          // 16 MB
  unsigned short* wbf = (unsigned short*)(ws + (16u << 20));         //  2 MB
  unsigned int* projP = (unsigned int*)(ws + (18u << 20));           // 16 MB
  float* part = (float*)(ws + (34u << 20));                          //  4 MB

  {
    int n4 = (BS * MD) / 4;  // 2097152
    cast_bf16_kernel<<<(n4 + 255) / 256, 256, 0, stream>>>(x, xb, n4);
  }
  {
    int n4 = (NO * MD) / 4;  // 262144
    cast_bf16_kernel<<<(n4 + 255) / 256, 256, 0, stream>>>(W, wbf, n4);
  }
  {
    dim3 grid(BS / 128, NO / 128);  // (64, 8)
    gemm_kernel<<<grid, 256, 0, stream>>>(xb, wbf, projP);
  }
  dist_kernel<<<32 * 32 * KSPLIT, 64, 0, stream>>>(projP, part);
  reduce_kernel<<<32, 256, 0, stream>>>(part, out);
}

// Round 4
// 171.919 us; speedup vs baseline: 1.1198x; 1.0372x over previous
//
#include <hip/hip_runtime.h>

// Problem: B=32, S=256, M=1024, N=32, O=32.
// out[b][s*32+o] = sum_k exp(-sum_n |proj[b,s,n,o]-proj[b,k,n,o]|),
// proj[b,s,j] = sum_m x[b,s,m] W[j,m],  j = n*32+o.

#define BS 8192      // B*S rows of x
#define MD 1024      // M
#define NO 1024      // N*O
#define KTILE 64     // k-tile per wave

typedef short short8 __attribute__((ext_vector_type(8)));    // 8 bf16 raw bits
typedef float f32x4 __attribute__((ext_vector_type(4)));
typedef _Float16 f16x2 __attribute__((ext_vector_type(2)));

template <typename T, typename F>
__device__ __forceinline__ T bc(F f) { return __builtin_bit_cast(T, f); }

// packed f16 ops pinned to the VOP3P instructions
__device__ __forceinline__ unsigned pk_max(unsigned a, unsigned b) {
  unsigned d;
  asm("v_pk_max_f16 %0, %1, %2" : "=v"(d) : "v"(a), "v"(b));
  return d;
}
__device__ __forceinline__ unsigned pk_add(unsigned a, unsigned b) {
  unsigned d;
  asm("v_pk_add_f16 %0, %1, %2" : "=v"(d) : "v"(a), "v"(b));
  return d;
}

// ---------------- cast f32 -> bf16 (RNE), 4 elems/thread ----------------
__global__ __launch_bounds__(256) void cast_bf16_kernel(const float* __restrict__ in,
                                                        unsigned short* __restrict__ out,
                                                        int n4) {
  int i = blockIdx.x * 256 + threadIdx.x;
  if (i >= n4) return;
  float4 v = reinterpret_cast<const float4*>(in)[i];
  ushort4 u;
  unsigned b;
  b = __float_as_uint(v.x); u.x = (unsigned short)((b + 0x7FFFu + ((b >> 16) & 1u)) >> 16);
  b = __float_as_uint(v.y); u.y = (unsigned short)((b + 0x7FFFu + ((b >> 16) & 1u)) >> 16);
  b = __float_as_uint(v.z); u.z = (unsigned short)((b + 0x7FFFu + ((b >> 16) & 1u)) >> 16);
  b = __float_as_uint(v.w); u.w = (unsigned short)((b + 0x7FFFu + ((b >> 16) & 1u)) >> 16);
  reinterpret_cast<ushort4*>(out)[i] = u;
}

// ---------------- GEMM: projT[j][i] = sum_k W[j,k] x[i,k], emitted as
// projP[m][o][i] = packed f16x2 (proj[n=2m], proj[n=2m+1]) for column o ----
__global__ __launch_bounds__(256) void gemm_kernel(const unsigned short* __restrict__ xb,
                                                   const unsigned short* __restrict__ wb,
                                                   unsigned int* __restrict__ projP) {
  const int lane = threadIdx.x & 63;
  const int w = threadIdx.x >> 6;
  const int wj = w >> 1, wi = w & 1;
  const int jt = blockIdx.y * 128 + wj * 64;   // multiple of 64
  const int it = blockIdx.x * 128 + wi * 64;
  const int c = lane & 15, h = lane >> 4;

  f32x4 acc[4][4];
#pragma unroll
  for (int m = 0; m < 4; m++)
#pragma unroll
    for (int n = 0; n < 4; n++) acc[m][n] = f32x4{0.f, 0.f, 0.f, 0.f};

  const unsigned short* wptr = wb + (size_t)(jt + c) * MD + h * 8;
  const unsigned short* xptr = xb + (size_t)(it + c) * MD + h * 8;

  for (int k0 = 0; k0 < MD; k0 += 32) {
    short8 a[4], bfr[4];
#pragma unroll
    for (int mm = 0; mm < 4; mm++)
      a[mm] = *reinterpret_cast<const short8*>(wptr + mm * 16 * MD + k0);
#pragma unroll
    for (int nn = 0; nn < 4; nn++)
      bfr[nn] = *reinterpret_cast<const short8*>(xptr + nn * 16 * MD + k0);
#pragma unroll
    for (int mm = 0; mm < 4; mm++)
#pragma unroll
      for (int nn = 0; nn < 4; nn++)
        acc[mm][nn] = __builtin_amdgcn_mfma_f32_16x16x32_bf16(a[mm], bfr[nn], acc[mm][nn], 0, 0, 0);
  }

  // epilogue: j = jt + 16*mm + 4*h + r -> n = j>>5 (pair), o = j&31
  const int mglob = jt >> 6;  // n-pair index
#pragma unroll
  for (int mm01 = 0; mm01 < 2; mm01++) {
#pragma unroll
    for (int r = 0; r < 4; r++) {
      const int o = mm01 * 16 + h * 4 + r;
      unsigned int* orow = projP + (size_t)(mglob * 32 + o) * BS + it + c;
#pragma unroll
      for (int nn = 0; nn < 4; nn++) {
        orow[nn * 16] = bc<unsigned int>(
            __builtin_amdgcn_cvt_pkrtz(acc[mm01][nn][r], acc[mm01 + 2][nn][r]));
      }
    }
  }
}

// ---------------- phase 2: distances + exp, packed f16 via asm ----------------
// 256-thread block per (b,o). Wave w handles k-quarter [64w,64w+64).
// Lane t owns rows i = t + 64*r (r=0..3), p2 pinned in VGPRs.
// Sum|a-b| = 2*Smax - A_i - A_k ; out += exp2((A_i+A_k-2S)*log2e)
__global__ __launch_bounds__(256) void dist_kernel(const unsigned int* __restrict__ projP,
                                                   float* __restrict__ out) {
  const int tid = threadIdx.x;
  const int t = tid & 63;   // lane
  const int w = tid >> 6;   // wave = k-quarter
  const int bid = blockIdx.x;
  const int o = bid & 31, b = bid >> 5;
  const int ibase = b * 256;

  __shared__ unsigned int kv_lds[4][16][KTILE];  // 16 KB
  __shared__ float A_lds[256];                   // 1 KB
  __shared__ float outp[4][256];                 // 4 KB

  // stage this wave's k-tile (coalesced, conflict-free)
#pragma unroll
  for (int m = 0; m < 16; m++)
    kv_lds[w][m][t] = projP[(size_t)(m * 32 + o) * BS + ibase + w * KTILE + t];

  // per-thread rows, pinned in VGPRs; A-chain bit-matches the k-loop pk_add chain
  unsigned p2[4][16];
  float Af[4];
#pragma unroll
  for (int r = 0; r < 4; r++) {
#pragma unroll
    for (int m = 0; m < 16; m++) {
      p2[r][m] = projP[(size_t)(m * 32 + o) * BS + ibase + t + 64 * r];
      asm("" : "+v"(p2[r][m]));  // force VGPR residency (VGPR=56 showed remat)
    }
    unsigned a2 = 0u;
#pragma unroll
    for (int m = 0; m < 16; m++) a2 = pk_add(a2, p2[r][m]);
    f16x2 af = bc<f16x2>(a2);
    Af[r] = (float)af[0] + (float)af[1];
  }
  A_lds[w * 64 + t] = Af[w];  // row w*64+t belongs to wave-w's k-tile
  __syncthreads();

  float outv[4] = {0.f, 0.f, 0.f, 0.f};
  for (int kk0 = 0; kk0 < KTILE; kk0 += 4) {
    unsigned s2[4][4];
#pragma unroll
    for (int r = 0; r < 4; r++)
#pragma unroll
      for (int q = 0; q < 4; q++) s2[r][q] = 0u;

#pragma unroll
    for (int m = 0; m < 16; m++) {
      uint4 kw = *reinterpret_cast<const uint4*>(&kv_lds[w][m][kk0]);  // broadcast b128
#pragma unroll
      for (int r = 0; r < 4; r++) {
        s2[r][0] = pk_add(s2[r][0], pk_max(p2[r][m], kw.x));
        s2[r][1] = pk_add(s2[r][1], pk_max(p2[r][m], kw.y));
        s2[r][2] = pk_add(s2[r][2], pk_max(p2[r][m], kw.z));
        s2[r][3] = pk_add(s2[r][3], pk_max(p2[r][m], kw.w));
      }
    }
    float4 ak = *reinterpret_cast<const float4*>(&A_lds[w * 64 + kk0]);
    float akv[4] = {ak.x, ak.y, ak.z, ak.w};
#pragma unroll
    for (int r = 0; r < 4; r++)
#pragma unroll
      for (int q = 0; q < 4; q++) {
        f16x2 sv = bc<f16x2>(s2[r][q]);
        float S = (float)sv[0] + (float)sv[1];
        outv[r] += exp2f((Af[r] + akv[q] - 2.0f * S) * 1.4426950408889634f);
      }
  }

  // cross-wave reduction over the 4 k-quarters, then direct store
#pragma unroll
  for (int r = 0; r < 4; r++) outp[w][t + 64 * r] = outv[r];
  __syncthreads();
  {
    int s = tid;  // 256 rows
    float v = outp[0][s] + outp[1][s] + outp[2][s] + outp[3][s];
    out[(size_t)b * 8192 + s * 32 + o] = v;
  }
}

extern "C" void kernel_launch(void* const* d_in, const int* in_sizes, int n_in,
                              void* d_out, int out_size, void* d_ws, size_t ws_size,
                              hipStream_t stream) {
  const float* x = (const float*)d_in[0];   // (32,256,1024) f32
  const float* W = (const float*)d_in[1];   // (1024,1024) f32
  float* out = (float*)d_out;               // (32, 8192) f32

  char* ws = (char*)d_ws;
  unsigned short* xb = (unsigned short*)ws;                          // 16 MB
  unsigned short* wbf = (unsigned short*)(ws + (16u << 20));         //  2 MB
  unsigned int* projP = (unsigned int*)(ws + (18u << 20));           // 16 MB

  {
    int n4 = (BS * MD) / 4;  // 2097152
    cast_bf16_kernel<<<(n4 + 255) / 256, 256, 0, stream>>>(x, xb, n4);
  }
  {
    int n4 = (NO * MD) / 4;  // 262144
    cast_bf16_kernel<<<(n4 + 255) / 256, 256, 0, stream>>>(W, wbf, n4);
  }
  {
    dim3 grid(BS / 128, NO / 128);  // (64, 8)
    gemm_kernel<<<grid, 256, 0, stream>>>(xb, wbf, projP);
  }
  dist_kernel<<<32 * 32, 256, 0, stream>>>(projP, out);
}

// Round 5
// 171.283 us; speedup vs baseline: 1.1239x; 1.0037x over previous
//
#include <hip/hip_runtime.h>

// Problem: B=32, S=256, M=1024, N=32, O=32.
// out[b][s*32+o] = sum_k exp(-sum_n |proj[b,s,n,o]-proj[b,k,n,o]|),
// proj[b,s,j] = sum_m x[b,s,m] W[j,m],  j = n*32+o.

#define BS 8192      // B*S rows of x
#define MD 1024      // M
#define NO 1024      // N*O

typedef short short8 __attribute__((ext_vector_type(8)));    // 8 bf16 raw bits
typedef float f32x4 __attribute__((ext_vector_type(4)));
typedef _Float16 f16x2 __attribute__((ext_vector_type(2)));

template <typename T, typename F>
__device__ __forceinline__ T bc(F f) { return __builtin_bit_cast(T, f); }

// packed f16 ops pinned to the VOP3P instructions
__device__ __forceinline__ unsigned pk_max(unsigned a, unsigned b) {
  unsigned d;
  asm("v_pk_max_f16 %0, %1, %2" : "=v"(d) : "v"(a), "v"(b));
  return d;
}
__device__ __forceinline__ unsigned pk_add(unsigned a, unsigned b) {
  unsigned d;
  asm("v_pk_add_f16 %0, %1, %2" : "=v"(d) : "v"(a), "v"(b));
  return d;
}

// ---------------- cast f32 -> bf16 (RNE), 4 elems/thread ----------------
__global__ __launch_bounds__(256) void cast_bf16_kernel(const float* __restrict__ in,
                                                        unsigned short* __restrict__ out,
                                                        int n4) {
  int i = blockIdx.x * 256 + threadIdx.x;
  if (i >= n4) return;
  float4 v = reinterpret_cast<const float4*>(in)[i];
  ushort4 u;
  unsigned b;
  b = __float_as_uint(v.x); u.x = (unsigned short)((b + 0x7FFFu + ((b >> 16) & 1u)) >> 16);
  b = __float_as_uint(v.y); u.y = (unsigned short)((b + 0x7FFFu + ((b >> 16) & 1u)) >> 16);
  b = __float_as_uint(v.z); u.z = (unsigned short)((b + 0x7FFFu + ((b >> 16) & 1u)) >> 16);
  b = __float_as_uint(v.w); u.w = (unsigned short)((b + 0x7FFFu + ((b >> 16) & 1u)) >> 16);
  reinterpret_cast<ushort4*>(out)[i] = u;
}

// ---------------- GEMM: projT[j][i] = sum_k W[j,k] x[i,k], emitted as
// projP[m][o][i] = packed f16x2 (proj[n=2m], proj[n=2m+1]) for column o ----
__global__ __launch_bounds__(256) void gemm_kernel(const unsigned short* __restrict__ xb,
                                                   const unsigned short* __restrict__ wb,
                                                   unsigned int* __restrict__ projP) {
  const int lane = threadIdx.x & 63;
  const int w = threadIdx.x >> 6;
  const int wj = w >> 1, wi = w & 1;
  const int jt = blockIdx.y * 128 + wj * 64;   // multiple of 64
  const int it = blockIdx.x * 128 + wi * 64;
  const int c = lane & 15, h = lane >> 4;

  f32x4 acc[4][4];
#pragma unroll
  for (int m = 0; m < 4; m++)
#pragma unroll
    for (int n = 0; n < 4; n++) acc[m][n] = f32x4{0.f, 0.f, 0.f, 0.f};

  const unsigned short* wptr = wb + (size_t)(jt + c) * MD + h * 8;
  const unsigned short* xptr = xb + (size_t)(it + c) * MD + h * 8;

  for (int k0 = 0; k0 < MD; k0 += 32) {
    short8 a[4], bfr[4];
#pragma unroll
    for (int mm = 0; mm < 4; mm++)
      a[mm] = *reinterpret_cast<const short8*>(wptr + mm * 16 * MD + k0);
#pragma unroll
    for (int nn = 0; nn < 4; nn++)
      bfr[nn] = *reinterpret_cast<const short8*>(xptr + nn * 16 * MD + k0);
#pragma unroll
    for (int mm = 0; mm < 4; mm++)
#pragma unroll
      for (int nn = 0; nn < 4; nn++)
        acc[mm][nn] = __builtin_amdgcn_mfma_f32_16x16x32_bf16(a[mm], bfr[nn], acc[mm][nn], 0, 0, 0);
  }

  // epilogue: j = jt + 16*mm + 4*h + r -> n = j>>5 (pair), o = j&31
  const int mglob = jt >> 6;  // n-pair index
#pragma unroll
  for (int mm01 = 0; mm01 < 2; mm01++) {
#pragma unroll
    for (int r = 0; r < 4; r++) {
      const int o = mm01 * 16 + h * 4 + r;
      unsigned int* orow = projP + (size_t)(mglob * 32 + o) * BS + it + c;
#pragma unroll
      for (int nn = 0; nn < 4; nn++) {
        orow[nn * 16] = bc<unsigned int>(
            __builtin_amdgcn_cvt_pkrtz(acc[mm01][nn][r], acc[mm01 + 2][nn][r]));
      }
    }
  }
}

// ---------------- A[o][gi] = f32 row-sum of packed f16 pairs ----------------
// MUST use the same ascending-m pk_add chain as dist's S-chain (diag exactness)
__global__ __launch_bounds__(256) void asum_kernel(const unsigned int* __restrict__ projP,
                                                   float* __restrict__ A) {
  int idx = blockIdx.x * 256 + threadIdx.x;   // 32*8192 total
  int gi = idx & 8191, o = idx >> 13;
  unsigned a2 = 0u;
#pragma unroll
  for (int m = 0; m < 16; m++)
    a2 = pk_add(a2, projP[(size_t)(m * 32 + o) * BS + gi]);
  f16x2 af = bc<f16x2>(a2);
  A[((size_t)o << 13) + gi] = (float)af[0] + (float)af[1];
}

// ---------------- phase 2: distances + exp, packed f16 via asm ----------------
// Block = (b, o, ihalf): 256 threads, wave w owns k-quarter [64w, 64w+64).
// Lane t owns rows i = ihalf*128 + t + 64r (r=0..1) -> p2[2][16] = 32 VGPR.
// Sum|a-b| = 2*Smax - A_i - A_k ; out += exp2((A_i+A_k-2S)*log2e)
__global__ __launch_bounds__(256, 6) void dist_kernel(const unsigned int* __restrict__ projP,
                                                      const float* __restrict__ A,
                                                      float* __restrict__ out) {
  const int tid = threadIdx.x;
  const int t = tid & 63;   // lane
  const int w = tid >> 6;   // wave = k-quarter
  const int bid = blockIdx.x;                   // 32b * 32o * 2ih
  const int ih = bid & 1, o = (bid >> 1) & 31, b = bid >> 6;
  const int ibase = b * 256;

  __shared__ unsigned int kv_lds[4][16][64];  // 16 KB
  __shared__ float A_lds[256];                // 1 KB: A for this b's 256 rows
  __shared__ float outp[4][128];              // 2 KB

  // stage this wave's k-tile + A (coalesced, conflict-free)
#pragma unroll
  for (int m = 0; m < 16; m++)
    kv_lds[w][m][t] = projP[(size_t)(m * 32 + o) * BS + ibase + w * 64 + t];
  A_lds[tid] = A[((size_t)o << 13) + ibase + tid];

  // per-thread rows (independent of LDS staging)
  unsigned p2[2][16];
#pragma unroll
  for (int r = 0; r < 2; r++)
#pragma unroll
    for (int m = 0; m < 16; m++)
      p2[r][m] = projP[(size_t)(m * 32 + o) * BS + ibase + ih * 128 + t + 64 * r];

  __syncthreads();
  const float Af0 = A_lds[ih * 128 + t];
  const float Af1 = A_lds[ih * 128 + t + 64];

  float outv0 = 0.f, outv1 = 0.f;
  for (int kk0 = 0; kk0 < 64; kk0 += 4) {
    unsigned s0[4] = {0u, 0u, 0u, 0u}, s1[4] = {0u, 0u, 0u, 0u};
#pragma unroll
    for (int m = 0; m < 16; m++) {
      uint4 kw = *reinterpret_cast<const uint4*>(&kv_lds[w][m][kk0]);  // broadcast b128
      s0[0] = pk_add(s0[0], pk_max(p2[0][m], kw.x));
      s0[1] = pk_add(s0[1], pk_max(p2[0][m], kw.y));
      s0[2] = pk_add(s0[2], pk_max(p2[0][m], kw.z));
      s0[3] = pk_add(s0[3], pk_max(p2[0][m], kw.w));
      s1[0] = pk_add(s1[0], pk_max(p2[1][m], kw.x));
      s1[1] = pk_add(s1[1], pk_max(p2[1][m], kw.y));
      s1[2] = pk_add(s1[2], pk_max(p2[1][m], kw.z));
      s1[3] = pk_add(s1[3], pk_max(p2[1][m], kw.w));
    }
    f32x4 ak = *reinterpret_cast<const f32x4*>(&A_lds[w * 64 + kk0]);
#pragma unroll
    for (int q = 0; q < 4; q++) {
      f16x2 sv0 = bc<f16x2>(s0[q]), sv1 = bc<f16x2>(s1[q]);
      float S0 = (float)sv0[0] + (float)sv0[1];
      float S1 = (float)sv1[0] + (float)sv1[1];
      outv0 += exp2f((Af0 + ak[q] - 2.0f * S0) * 1.4426950408889634f);
      outv1 += exp2f((Af1 + ak[q] - 2.0f * S1) * 1.4426950408889634f);
    }
  }

  // cross-wave reduction over the 4 k-quarters, then direct store
  outp[w][t] = outv0;
  outp[w][t + 64] = outv1;
  __syncthreads();
  if (tid < 128) {
    float v = outp[0][tid] + outp[1][tid] + outp[2][tid] + outp[3][tid];
    out[(size_t)b * 8192 + (size_t)(ih * 128 + tid) * 32 + o] = v;
  }
}

extern "C" void kernel_launch(void* const* d_in, const int* in_sizes, int n_in,
                              void* d_out, int out_size, void* d_ws, size_t ws_size,
                              hipStream_t stream) {
  const float* x = (const float*)d_in[0];   // (32,256,1024) f32
  const float* W = (const float*)d_in[1];   // (1024,1024) f32
  float* out = (float*)d_out;               // (32, 8192) f32

  char* ws = (char*)d_ws;
  unsigned short* xb = (unsigned short*)ws;                          // 16 MB
  unsigned short* wbf = (unsigned short*)(ws + (16u << 20));         //  2 MB
  unsigned int* projP = (unsigned int*)(ws + (18u << 20));           // 16 MB
  float* Abuf = (float*)(ws + (34u << 20));                          //  1 MB

  {
    int n4 = (BS * MD) / 4;  // 2097152
    cast_bf16_kernel<<<(n4 + 255) / 256, 256, 0, stream>>>(x, xb, n4);
  }
  {
    int n4 = (NO * MD) / 4;  // 262144
    cast_bf16_kernel<<<(n4 + 255) / 256, 256, 0, stream>>>(W, wbf, n4);
  }
  {
    dim3 grid(BS / 128, NO / 128);  // (64, 8)
    gemm_kernel<<<grid, 256, 0, stream>>>(xb, wbf, projP);
  }
  asum_kernel<<<(32 * BS) / 256, 256, 0, stream>>>(projP, Abuf);
  dist_kernel<<<32 * 32 * 2, 256, 0, stream>>>(projP, Abuf, out);
}